// Round 2
// baseline (393.058 us; speedup 1.0000x reference)
//
#include <hip/hip_runtime.h>
#include <hip/hip_bf16.h>
#include <math.h>

#define T_LEN 1024
#define D_DIM 64
#define BATCH 32

#define SLACK_FRONT 64           // rows of +INF before each batch matrix
#define SLACK_BACK  72           // in-bounds don't-care rows after last matrix
#define ROW_STRIDE  (T_LEN + SLACK_FRONT)   // 1088 rows per batch segment
#define PD 8                     // prefetch depth (steps)

// ---------------------------------------------------------------------------
// Fill the 64-row front-slack region of each batch segment with +INF.
// Must run every launch (harness re-poisons d_ws with 0xAA = finite negative).
// grid 2048 x 256, one float4 per thread.
// ---------------------------------------------------------------------------
__global__ __launch_bounds__(256) void fill_slack_kernel(float* __restrict__ ws) {
    int g = blockIdx.x * 256 + threadIdx.x;      // 0 .. 32*16384-1
    int b = g >> 14;                             // 16384 float4 per slack region
    int off = g & 16383;
    float4* dst = (float4*)(ws + (size_t)b * (ROW_STRIDE * T_LEN)) + off;
    const float INF = __builtin_inff();
    *dst = make_float4(INF, INF, INF, INF);
}

// ---------------------------------------------------------------------------
// Pairwise distances, 128x128 tile, 256 threads, 8x8 micro-tile, BK=32 x2.
// Wave laid out as 8x8 so LDS read strides are <=2-way (free).
// batch_stride_f selects compact (1024*1024) or strided (1088*1024) layout.
// ---------------------------------------------------------------------------
__global__ __launch_bounds__(256) void cost_kernel(const float* __restrict__ pred,
                                                   const float* __restrict__ targ,
                                                   float* __restrict__ cost_base,
                                                   unsigned long long batch_stride_f) {
    const int b = blockIdx.z;
    const float* P = pred + (size_t)b * T_LEN * D_DIM;
    const float* T = targ + (size_t)b * T_LEN * D_DIM;
    float* C = cost_base + (size_t)b * batch_stride_f;
    const int row0 = blockIdx.y * 128;
    const int col0 = blockIdx.x * 128;

    __shared__ __align__(16) float ps[32][132];  // ps[kk][r] = P[row0+r][k0+kk]
    __shared__ __align__(16) float ts[32][132];
    __shared__ float p2[128], t2[128];

    const int tid = threadIdx.x;

    // Squared norms straight from global (rows are L2-warm; coalesced float4).
    {
        int r = tid & 127;
        const float* src = (tid < 128) ? (P + (size_t)(row0 + r) * D_DIM)
                                       : (T + (size_t)(col0 + r) * D_DIM);
        float s = 0.0f;
#pragma unroll
        for (int q = 0; q < 16; q++) {
            float4 v = ((const float4*)src)[q];
            s += v.x * v.x + v.y * v.y + v.z * v.z + v.w * v.w;
        }
        if (tid < 128) p2[r] = s; else t2[r] = s;
    }

    const int lane = tid & 63, wv = tid >> 6;
    const int TX = (lane & 7) + 8 * (wv & 1);    // 0..15
    const int TY = (lane >> 3) + 8 * (wv >> 1);  // 0..15

    float acc[8][8];
#pragma unroll
    for (int i = 0; i < 8; i++)
#pragma unroll
        for (int j = 0; j < 8; j++) acc[i][j] = 0.0f;

#pragma unroll
    for (int chunk = 0; chunk < 2; ++chunk) {
        __syncthreads();
        // Stage 128 rows x 32 k, K-major, both sides.
#pragma unroll
        for (int it = 0; it < 4; ++it) {
            int idx = tid + 256 * it;            // 0..1023
            int row = idx >> 3;                  // 0..127
            int kc = idx & 7;                    // float4 chunk within 32-k
            float4 v = *(const float4*)(P + (size_t)(row0 + row) * D_DIM + 32 * chunk + 4 * kc);
            ps[4 * kc + 0][row] = v.x; ps[4 * kc + 1][row] = v.y;
            ps[4 * kc + 2][row] = v.z; ps[4 * kc + 3][row] = v.w;
            float4 w = *(const float4*)(T + (size_t)(col0 + row) * D_DIM + 32 * chunk + 4 * kc);
            ts[4 * kc + 0][row] = w.x; ts[4 * kc + 1][row] = w.y;
            ts[4 * kc + 2][row] = w.z; ts[4 * kc + 3][row] = w.w;
        }
        __syncthreads();

#pragma unroll
        for (int kk = 0; kk < 32; ++kk) {
            float4 a0 = *(const float4*)&ps[kk][8 * TY];
            float4 a1 = *(const float4*)&ps[kk][8 * TY + 4];
            float4 b0 = *(const float4*)&ts[kk][8 * TX];
            float4 b1 = *(const float4*)&ts[kk][8 * TX + 4];
            float av[8] = {a0.x, a0.y, a0.z, a0.w, a1.x, a1.y, a1.z, a1.w};
            float bv[8] = {b0.x, b0.y, b0.z, b0.w, b1.x, b1.y, b1.z, b1.w};
#pragma unroll
            for (int i = 0; i < 8; i++)
#pragma unroll
                for (int j = 0; j < 8; j++) acc[i][j] += av[i] * bv[j];
        }
    }
    __syncthreads();

#pragma unroll
    for (int i = 0; i < 8; i++) {
        float pa = p2[8 * TY + i];
        float o[8];
#pragma unroll
        for (int j = 0; j < 8; j++) {
            float d = pa + t2[8 * TX + j] - 2.0f * acc[i][j];
            o[j] = sqrtf(fmaxf(d, 1e-12f));
        }
        float* dst = C + (size_t)(row0 + 8 * TY + i) * T_LEN + col0 + 8 * TX;
        ((float4*)dst)[0] = make_float4(o[0], o[1], o[2], o[3]);
        ((float4*)dst)[1] = make_float4(o[4], o[5], o[6], o[7]);
    }
}

// ---------------------------------------------------------------------------
// Branchless Frechet DP, one wave per batch, strided layout with INF slack.
// Chain per cell is ONE med3: max(c,min(e,x)) == med3(c, max(e,c), x).
// __launch_bounds__(64,1): single wave, allow full VGPR budget so the
// 8-deep float4[4] prefetch pipeline stays in registers.
// ---------------------------------------------------------------------------
__global__ __launch_bounds__(64, 1) void dp_kernel_nb(const float* __restrict__ cost,
                                                      float* __restrict__ out) {
    const int b = blockIdx.x;
    const int t = threadIdx.x;
    const float INF = __builtin_inff();
    const float* Cl = cost + ((size_t)SLACK_FRONT + (size_t)b * ROW_STRIDE) * T_LEN + 16 * t;

    float prev[16];
#pragma unroll
    for (int j = 0; j < 16; j++) prev[j] = INF;
    float right_out = INF;
    float diag_feed = INF;
    float lane0_left = -INF;   // -INF only for the very first step (r==0,t==0)

    float4 pipe[PD][4];
    const float* ptr[PD];
#pragma unroll
    for (int d = 0; d < PD; d++) {
        const float* p = Cl + (ptrdiff_t)(d - t) * T_LEN;
        const float4* p4 = (const float4*)p;
        pipe[d][0] = p4[0]; pipe[d][1] = p4[1]; pipe[d][2] = p4[2]; pipe[d][3] = p4[3];
        ptr[d] = Cl + (ptrdiff_t)(d + PD - t) * T_LEN;
    }

    // 135 full chunks of 8 steps = s 0..1079
    for (int chunk = 0; chunk < 135; ++chunk) {
#pragma unroll
        for (int u = 0; u < PD; u++) {
            float inc = __shfl_up(right_out, 1, 64);
            float left = (t == 0) ? lane0_left : inc;
            float diag = (t == 0) ? INF : diag_feed;
            diag_feed = inc;
            const float* cb = (const float*)&pipe[u][0];
#pragma unroll
            for (int j = 0; j < 16; j++) {
                float c = cb[j];
                float e = fminf(prev[j], diag);       // off-chain
                float h = fmaxf(e, c);                // off-chain
                float v = __builtin_amdgcn_fmed3f(c, h, left);  // 1 op on chain
                diag = prev[j];
                prev[j] = v;
                left = v;
            }
            right_out = left;
            lane0_left = INF;
            // reload pipe[u] for step s+PD: pure pointer bump, no clamp/branch
            const float4* p4 = (const float4*)ptr[u];
            pipe[u][0] = p4[0]; pipe[u][1] = p4[1]; pipe[u][2] = p4[2]; pipe[u][3] = p4[3];
            ptr[u] += PD * T_LEN;
        }
    }
    // remainder: s = 1080..1086, data already in pipe[0..6], no reloads
#pragma unroll
    for (int u = 0; u < 7; u++) {
        float inc = __shfl_up(right_out, 1, 64);
        float left = (t == 0) ? lane0_left : inc;
        float diag = (t == 0) ? INF : diag_feed;
        diag_feed = inc;
        const float* cb = (const float*)&pipe[u][0];
#pragma unroll
        for (int j = 0; j < 16; j++) {
            float c = cb[j];
            float e = fminf(prev[j], diag);
            float h = fmaxf(e, c);
            float v = __builtin_amdgcn_fmed3f(c, h, left);
            diag = prev[j];
            prev[j] = v;
            left = v;
        }
        right_out = left;
        lane0_left = INF;
    }

    if (t == 63) atomicAdd(out, prev[15] * (1.0f / (float)BATCH));
}

// ---------------------------------------------------------------------------
// Fallback: clamped/guarded DP on compact layout (if ws too small for slack).
// ---------------------------------------------------------------------------
__global__ __launch_bounds__(64, 1) void dp_kernel_clamped(const float* __restrict__ cost,
                                                           float* __restrict__ out) {
    const int b = blockIdx.x;
    const int t = threadIdx.x;
    const float INF = __builtin_inff();
    const float* C = cost + (size_t)b * T_LEN * T_LEN + 16 * t;

    float prev[16];
#pragma unroll
    for (int j = 0; j < 16; j++) prev[j] = INF;
    float right_out = INF;
    float diag_feed = INF;

    float4 pipe[PD][4];
#pragma unroll
    for (int d = 0; d < PD; d++) {
        int r = d - t; r = r < 0 ? 0 : (r > T_LEN - 1 ? T_LEN - 1 : r);
        const float4* p = (const float4*)(C + (size_t)r * T_LEN);
        pipe[d][0] = p[0]; pipe[d][1] = p[1]; pipe[d][2] = p[2]; pipe[d][3] = p[3];
    }

    const int S = T_LEN + 63;
    const int NCH = (S + PD - 1) / PD;
    int s = 0;
    for (int chunk = 0; chunk < NCH; chunk++) {
#pragma unroll
        for (int u = 0; u < PD; u++, s++) {
            int r = s - t;
            float inc = __shfl_up(right_out, 1, 64);
            float left = inc, diag = diag_feed;
            diag_feed = inc;
            if (t == 0) { left = (r == 0) ? -INF : INF; diag = INF; }
            if (r >= 0 && r < T_LEN) {
                const float* cb = (const float*)&pipe[u][0];
#pragma unroll
                for (int j = 0; j < 16; j++) {
                    float c = cb[j];
                    float e = fminf(prev[j], diag);
                    float h = fmaxf(e, c);
                    float v = __builtin_amdgcn_fmed3f(c, h, left);
                    diag = prev[j];
                    prev[j] = v;
                    left = v;
                }
                right_out = left;
            }
            int rn = s + PD - t; rn = rn < 0 ? 0 : (rn > T_LEN - 1 ? T_LEN - 1 : rn);
            const float4* p = (const float4*)(C + (size_t)rn * T_LEN);
            pipe[u][0] = p[0]; pipe[u][1] = p[1]; pipe[u][2] = p[2]; pipe[u][3] = p[3];
        }
    }
    if (t == 63) atomicAdd(out, prev[15] * (1.0f / (float)BATCH));
}

// ---------------------------------------------------------------------------
// Last-resort fused fallback (ws can't hold one matrix).
// ---------------------------------------------------------------------------
__global__ __launch_bounds__(64) void dp_fused_kernel(const float* __restrict__ pred,
                                                      const float* __restrict__ targ,
                                                      float* __restrict__ out) {
    const int b = blockIdx.x;
    const int t = threadIdx.x;
    const float INF = __builtin_inff();
    const float* P = pred + (size_t)b * T_LEN * D_DIM;
    const float* T = targ + (size_t)b * T_LEN * D_DIM + (size_t)(16 * t) * D_DIM;

    float prev[16];
#pragma unroll
    for (int j = 0; j < 16; j++) prev[j] = INF;
    float right_out = INF;
    float diag_feed = INF;

    for (int s = 0; s < T_LEN + 63; s++) {
        int r = s - t;
        float inc = __shfl_up(right_out, 1, 64);
        float left = inc, diag = diag_feed;
        diag_feed = inc;
        if (t == 0) { left = (r == 0) ? -INF : INF; diag = INF; }
        if (r >= 0 && r < T_LEN) {
            float4 pr[16];
            const float4* pp = (const float4*)(P + (size_t)r * D_DIM);
#pragma unroll
            for (int q = 0; q < 16; q++) pr[q] = pp[q];
#pragma unroll
            for (int j = 0; j < 16; j++) {
                const float4* tp = (const float4*)(T + (size_t)j * D_DIM);
                float acc = 0.0f;
#pragma unroll
                for (int q = 0; q < 16; q++) {
                    float4 tv = tp[q];
                    float dx = pr[q].x - tv.x; acc += dx * dx;
                    float dy = pr[q].y - tv.y; acc += dy * dy;
                    float dz = pr[q].z - tv.z; acc += dz * dz;
                    float dw = pr[q].w - tv.w; acc += dw * dw;
                }
                float c = sqrtf(fmaxf(acc, 1e-12f));
                float e = fminf(prev[j], diag);
                float h = fmaxf(e, c);
                float v = __builtin_amdgcn_fmed3f(c, h, left);
                diag = prev[j];
                prev[j] = v;
                left = v;
            }
            right_out = left;
        }
    }
    if (t == 63) atomicAdd(out, prev[15] * (1.0f / (float)BATCH));
}

extern "C" void kernel_launch(void* const* d_in, const int* in_sizes, int n_in,
                              void* d_out, int out_size, void* d_ws, size_t ws_size,
                              hipStream_t stream) {
    const float* pred = (const float*)d_in[0];
    const float* targ = (const float*)d_in[1];
    float* out = (float*)d_out;

    hipMemsetAsync(out, 0, sizeof(float) * out_size, stream);

    // strided layout: 32 segments of 1088 rows (64 INF slack + 1024 matrix)
    // + 72 trailing don't-care rows
    const size_t need_strided = ((size_t)BATCH * ROW_STRIDE + SLACK_BACK) * (size_t)T_LEN * sizeof(float);
    const size_t per_batch_compact = (size_t)T_LEN * T_LEN * sizeof(float);

    if (ws_size >= need_strided) {
        float* ws = (float*)d_ws;
        fill_slack_kernel<<<2048, 256, 0, stream>>>(ws);
        float* cost_base = ws + (size_t)SLACK_FRONT * T_LEN;
        dim3 grid(8, 8, BATCH);
        cost_kernel<<<grid, 256, 0, stream>>>(pred, targ, cost_base,
                                              (unsigned long long)ROW_STRIDE * T_LEN);
        dp_kernel_nb<<<BATCH, 64, 0, stream>>>(ws, out);
    } else {
        int bpg = (int)(ws_size / per_batch_compact);
        if (bpg > BATCH) bpg = BATCH;
        if (bpg >= 1) {
            float* cost = (float*)d_ws;
            for (int g0 = 0; g0 < BATCH; g0 += bpg) {
                int gb = (BATCH - g0) < bpg ? (BATCH - g0) : bpg;
                dim3 grid(8, 8, gb);
                cost_kernel<<<grid, 256, 0, stream>>>(pred + (size_t)g0 * T_LEN * D_DIM,
                                                      targ + (size_t)g0 * T_LEN * D_DIM,
                                                      cost,
                                                      (unsigned long long)T_LEN * T_LEN);
                dp_kernel_clamped<<<gb, 64, 0, stream>>>(cost, out);
            }
        } else {
            dp_fused_kernel<<<BATCH, 64, 0, stream>>>(pred, targ, out);
        }
    }
}